// Round 1
// baseline (370.518 us; speedup 1.0000x reference)
//
#include <hip/hip_runtime.h>
#include <stdint.h>

typedef __bf16 bf16_t;
typedef bf16_t bf16x8 __attribute__((ext_vector_type(8)));
typedef float f32x4 __attribute__((ext_vector_type(4)));

#define NB 16
#define NQ 2048
#define NK 2048
#define ND 512
#define SCALE 0.04419417382415922f  // 1/sqrt(512)

__device__ __forceinline__ float4 ld4(const float* p) { return *(const float4*)p; }

__device__ __forceinline__ f32x4 mfma16(bf16x8 a, bf16x8 b, f32x4 c) {
  return __builtin_amdgcn_mfma_f32_16x16x32_bf16(a, b, c, 0, 0, 0);
}

// ---------------------------------------------------------------------------
// Kernel 0: V [B][K][D] fp32  ->  VT bf16 tiles, tile (b,kb) covers k in
// [kb*32, kb*32+32), all 512 d. Within a tile the layout is the exact LDS
// image kernel 2 wants (128B super-row = 2 d's, 16B chunks XOR-swizzled):
//   chunk(d, g) holds V[k0+g*8+j][d], j=0..7
//   chunk index = (d>>1)*8 + ((((d&1)<<2)|g) ^ ((d>>1)&7))
// ---------------------------------------------------------------------------
__global__ __launch_bounds__(256) void vt_kernel(const float* __restrict__ V,
                                                 bf16_t* __restrict__ VT,
                                                 const int* __restrict__ lens) {
  int kb = blockIdx.x, b = blockIdx.y;
  if (kb * 32 >= lens[b]) return;  // never read by kernel 2
  const float* vsrc = V + ((size_t)b * NK + kb * 32) * ND;
  bf16_t* dst = VT + ((size_t)(b * 64 + kb)) * (512 * 32);
  __shared__ alignas(16) bf16_t Ls[32][128];
  int t = threadIdx.x;
  for (int dbase = 0; dbase < ND; dbase += 128) {
#pragma unroll
    for (int i = 0; i < 4; ++i) {
      int p = i * 256 + t;          // float4 id 0..1023
      int k = p >> 5, c4 = p & 31;  // 32 float4 per k-row
      float4 v = ld4(vsrc + (size_t)k * ND + dbase + c4 * 4);
      union { bf16_t h[4]; uint2 u; } pk;
      pk.h[0] = (bf16_t)v.x; pk.h[1] = (bf16_t)v.y;
      pk.h[2] = (bf16_t)v.z; pk.h[3] = (bf16_t)v.w;
      *(uint2*)(&Ls[k][c4 * 4]) = pk.u;
    }
    __syncthreads();
    int d = dbase + (t >> 1);
    int h = t & 1;
    int sr = d >> 1;
#pragma unroll
    for (int gg = 0; gg < 2; ++gg) {
      int g = h * 2 + gg;
      bf16x8 v;
#pragma unroll
      for (int j = 0; j < 8; ++j) v[j] = Ls[g * 8 + j][d - dbase];
      int slot = (((d & 1) << 2) | g) ^ (sr & 7);
      *(bf16x8*)(dst + ((size_t)sr * 8 + slot) * 8) = v;
    }
    __syncthreads();
  }
}

// ---------------------------------------------------------------------------
// Kernel 1: per block (b, qtile128, khalf512): S = (Q K^T)*scale over a
// 128x512 stripe; P = exp(S) (0 where col>=len); writes unnormalized P to the
// weights region and per-row partial sums to ws psum[kh][b][q].
// 4 waves (2x2), 128x128 tile per ktile, BK=64, dbuf LDS, fp32->bf16
// reg-staged, XOR-swizzled 128B LDS rows.
// ---------------------------------------------------------------------------
__global__ __launch_bounds__(256, 2) void qk_kernel(const float* __restrict__ Q,
                                                    const float* __restrict__ Km,
                                                    float* __restrict__ P,
                                                    float* __restrict__ psum,
                                                    const int* __restrict__ lens) {
  int qt = blockIdx.x & 15;
  int kh = blockIdx.x >> 4;
  int b = blockIdx.y;
  int len = lens[b];
  int q0 = qt * 128;
  int khbase = kh * 512;

  __shared__ alignas(16) bf16_t As[2][128 * 64];
  __shared__ alignas(16) bf16_t Bs[2][128 * 64];

  int t = threadIdx.x;
  int lane = t & 63;
  int wid = t >> 6;
  int wm = wid >> 1, wn = wid & 1;
  int l15 = lane & 15, l4 = lane >> 4;

  const float* qsrc = Q + ((size_t)b * NQ + q0) * ND;
  float* prow = P + ((size_t)b * NQ + q0) * NK;

  float rsum[4][4];
#pragma unroll
  for (int mi = 0; mi < 4; ++mi)
#pragma unroll
    for (int r = 0; r < 4; ++r) rsum[mi][r] = 0.f;

  int rbase = wm * 64 + l4 * 4;

  for (int kt = 0; kt < 4; ++kt) {
    int col0 = khbase + kt * 128;
    if (col0 >= len) {  // fully masked tile: just write zeros
      float4 z = make_float4(0.f, 0.f, 0.f, 0.f);
#pragma unroll
      for (int i = 0; i < 16; ++i) {
        int p = i * 256 + t;
        int row = p >> 5, c4 = p & 31;
        *(float4*)(prow + (size_t)row * NK + col0 + c4 * 4) = z;
      }
      continue;
    }
    const float* ksrc = Km + ((size_t)b * NK + col0) * ND;

    f32x4 acc[4][4];
    f32x4 zz = {0.f, 0.f, 0.f, 0.f};
#pragma unroll
    for (int mi = 0; mi < 4; ++mi)
#pragma unroll
      for (int ni = 0; ni < 4; ++ni) acc[mi][ni] = zz;

    float4 qr[8], kr[8];

    auto loadregs = [&](int d0) {
#pragma unroll
      for (int i = 0; i < 4; ++i) {
        int G = i * 256 + t;         // 8-float group 0..1023
        int row = G >> 3, sl = G & 7;
        const float* a = qsrc + (size_t)row * ND + d0 + sl * 8;
        const float* c = ksrc + (size_t)row * ND + d0 + sl * 8;
        qr[2 * i] = ld4(a); qr[2 * i + 1] = ld4(a + 4);
        kr[2 * i] = ld4(c); kr[2 * i + 1] = ld4(c + 4);
      }
    };
    auto writebuf = [&](int buf) {
#pragma unroll
      for (int i = 0; i < 4; ++i) {
        int G = i * 256 + t;
        int row = G >> 3, sl = G & 7;
        int off = row * 64 + ((sl ^ (row & 7)) * 8);
        bf16x8 va, vb;
        float4 a0 = qr[2 * i], a1 = qr[2 * i + 1];
        float4 b0 = kr[2 * i], b1 = kr[2 * i + 1];
        va[0]=(bf16_t)a0.x; va[1]=(bf16_t)a0.y; va[2]=(bf16_t)a0.z; va[3]=(bf16_t)a0.w;
        va[4]=(bf16_t)a1.x; va[5]=(bf16_t)a1.y; va[6]=(bf16_t)a1.z; va[7]=(bf16_t)a1.w;
        vb[0]=(bf16_t)b0.x; vb[1]=(bf16_t)b0.y; vb[2]=(bf16_t)b0.z; vb[3]=(bf16_t)b0.w;
        vb[4]=(bf16_t)b1.x; vb[5]=(bf16_t)b1.y; vb[6]=(bf16_t)b1.z; vb[7]=(bf16_t)b1.w;
        *(bf16x8*)(&As[buf][off]) = va;
        *(bf16x8*)(&Bs[buf][off]) = vb;
      }
    };
    auto compute = [&](int cur) {
      bf16x8 af[4][2], bv[4][2];
#pragma unroll
      for (int mi = 0; mi < 4; ++mi) {
        int row = wm * 64 + mi * 16 + l15;
#pragma unroll
        for (int ks = 0; ks < 2; ++ks)
          af[mi][ks] = *(const bf16x8*)(&As[cur][row * 64 + (((ks * 4 + l4) ^ (row & 7)) * 8)]);
      }
#pragma unroll
      for (int ni = 0; ni < 4; ++ni) {
        int row = wn * 64 + ni * 16 + l15;
#pragma unroll
        for (int ks = 0; ks < 2; ++ks)
          bv[ni][ks] = *(const bf16x8*)(&Bs[cur][row * 64 + (((ks * 4 + l4) ^ (row & 7)) * 8)]);
      }
#pragma unroll
      for (int mi = 0; mi < 4; ++mi)
#pragma unroll
        for (int ni = 0; ni < 4; ++ni) {
          acc[mi][ni] = mfma16(af[mi][0], bv[ni][0], acc[mi][ni]);
          acc[mi][ni] = mfma16(af[mi][1], bv[ni][1], acc[mi][ni]);
        }
    };

    loadregs(0);
    writebuf(0);
    __syncthreads();
    for (int ds = 0; ds < 8; ++ds) {
      int cur = ds & 1;
      if (ds < 7) loadregs((ds + 1) * 64);  // issue next loads early (T14)
      compute(cur);
      if (ds < 7) writebuf(cur ^ 1);
      __syncthreads();
    }

    // epilogue: scale, mask, exp, rowsum, store unnormalized P
#pragma unroll
    for (int mi = 0; mi < 4; ++mi) {
#pragma unroll
      for (int ni = 0; ni < 4; ++ni) {
        int col = col0 + wn * 64 + ni * 16 + l15;
        bool valid = col < len;
#pragma unroll
        for (int r = 0; r < 4; ++r) {
          float e = valid ? __expf(acc[mi][ni][r] * SCALE) : 0.f;
          rsum[mi][r] += e;
          prow[(size_t)(rbase + mi * 16 + r) * NK + col] = e;
        }
      }
    }
  }

  // reduce partial row sums across the 16 col-lanes, then across wn
#pragma unroll
  for (int off = 1; off < 16; off <<= 1)
#pragma unroll
    for (int mi = 0; mi < 4; ++mi)
#pragma unroll
      for (int r = 0; r < 4; ++r)
        rsum[mi][r] += __shfl_xor(rsum[mi][r], off, 64);

  float* rsm = (float*)&As[0][0];  // LDS reuse (all tile reads are fenced)
  if (wn == 0 && l15 == 0) {
#pragma unroll
    for (int mi = 0; mi < 4; ++mi)
#pragma unroll
      for (int r = 0; r < 4; ++r) rsm[rbase + mi * 16 + r] = rsum[mi][r];
  }
  __syncthreads();
  if (wn == 1 && l15 == 0) {
#pragma unroll
    for (int mi = 0; mi < 4; ++mi)
#pragma unroll
      for (int r = 0; r < 4; ++r) {
        int row = rbase + mi * 16 + r;
        psum[((size_t)kh * 16 + b) * NQ + q0 + row] = rsum[mi][r] + rsm[row];
      }
  }
}

// ---------------------------------------------------------------------------
// Kernel 2: per block (b, qtile64): context[64][512] = Wnorm x V, reading
// unnormalized P once, normalizing in-flight (x 1/rowsum), writing normalized
// weights back in place and context out. BN=512 (full D) -> P read exactly
// once. Skips k-steps >= ceil(len/32) (P there is exactly 0 already).
// 8 waves, each waves rows 0..63 x cols w*64..+64; BK=32.
// ---------------------------------------------------------------------------
__global__ __launch_bounds__(512, 2) void pv_kernel(float* __restrict__ P,
                                                    const bf16_t* __restrict__ VT,
                                                    float* __restrict__ ctx,
                                                    const float* __restrict__ psum,
                                                    const int* __restrict__ lens) {
  int qt = blockIdx.x, b = blockIdx.y;
  int q0 = qt * 64;
  int len = lens[b];
  int nsteps = (len + 31) >> 5;

  __shared__ alignas(16) bf16_t Ps[2][64 * 32];
  __shared__ alignas(16) bf16_t Vs[2][512 * 32];
  __shared__ float rcp[64];

  int t = threadIdx.x;
  if (t < 64) {
    float s = 0.f;
#pragma unroll
    for (int i = 0; i < 4; ++i) s += psum[((size_t)i * 16 + b) * NQ + q0 + t];
    rcp[t] = 1.0f / s;
  }
  __syncthreads();

  float* prow = P + ((size_t)b * NQ + q0) * NK;
  const bf16_t* vtb = VT + ((size_t)b * 64) * (512 * 32);

  int lane = t & 63, wid = t >> 6;
  int l15 = lane & 15, l4 = lane >> 4;

  f32x4 acc[4][4];
  f32x4 zz = {0.f, 0.f, 0.f, 0.f};
#pragma unroll
  for (int mi = 0; mi < 4; ++mi)
#pragma unroll
    for (int ni = 0; ni < 4; ++ni) acc[mi][ni] = zz;

  int srow = t >> 3, sc4 = t & 7;
  float rr = rcp[srow];

  float4 pld;
  bf16x8 vld[4];

  auto stage_load = [&](int ks) {
    pld = ld4(prow + (size_t)srow * NK + ks * 32 + sc4 * 4);
    const bf16_t* src = vtb + (size_t)ks * (512 * 32);
#pragma unroll
    for (int i = 0; i < 4; ++i)
      vld[i] = *(const bf16x8*)(src + ((size_t)i * 512 + t) * 8);
  };
  auto stage_finish = [&](int ks, int buf) {
    float4 w;
    w.x = pld.x * rr; w.y = pld.y * rr; w.z = pld.z * rr; w.w = pld.w * rr;
    *(float4*)(prow + (size_t)srow * NK + ks * 32 + sc4 * 4) = w;  // normalized W out
    int sr = srow >> 1;
    int slot = (((srow & 1) << 2) | (sc4 >> 1)) ^ (sr & 7);
    union { bf16_t h[4]; uint2 u; } pk;
    pk.h[0] = (bf16_t)w.x; pk.h[1] = (bf16_t)w.y;
    pk.h[2] = (bf16_t)w.z; pk.h[3] = (bf16_t)w.w;
    *(uint2*)(&Ps[buf][((size_t)sr * 8 + slot) * 8 + (sc4 & 1) * 4]) = pk.u;
#pragma unroll
    for (int i = 0; i < 4; ++i)
      *(bf16x8*)(&Vs[buf][((size_t)i * 512 + t) * 8]) = vld[i];
  };
  auto compute = [&](int cur) {
    bf16x8 af[4], bv[4];
#pragma unroll
    for (int mi = 0; mi < 4; ++mi) {
      int row = mi * 16 + l15;
      af[mi] = *(const bf16x8*)(&Ps[cur][((row >> 1) * 8 + ((((row & 1) << 2) | l4) ^ ((row >> 1) & 7))) * 8]);
    }
#pragma unroll
    for (int ni = 0; ni < 4; ++ni) {
      int d = wid * 64 + ni * 16 + l15;
      bv[ni] = *(const bf16x8*)(&Vs[cur][((d >> 1) * 8 + ((((d & 1) << 2) | l4) ^ ((d >> 1) & 7))) * 8]);
    }
#pragma unroll
    for (int mi = 0; mi < 4; ++mi)
#pragma unroll
      for (int ni = 0; ni < 4; ++ni)
        acc[mi][ni] = mfma16(af[mi], bv[ni], acc[mi][ni]);
  };

  stage_load(0);
  stage_finish(0, 0);
  __syncthreads();
  for (int ks = 0; ks < nsteps; ++ks) {
    int cur = ks & 1;
    if (ks + 1 < nsteps) stage_load(ks + 1);  // issue early
    compute(cur);
    if (ks + 1 < nsteps) stage_finish(ks + 1, cur ^ 1);
    __syncthreads();
  }

  float* crow = ctx + ((size_t)b * NQ + q0) * ND + wid * 64;
#pragma unroll
  for (int mi = 0; mi < 4; ++mi)
#pragma unroll
    for (int ni = 0; ni < 4; ++ni)
#pragma unroll
      for (int r = 0; r < 4; ++r)
        crow[(size_t)(mi * 16 + l4 * 4 + r) * ND + ni * 16 + l15] = acc[mi][ni][r];
}

// ---------------------------------------------------------------------------
extern "C" void kernel_launch(void* const* d_in, const int* in_sizes, int n_in,
                              void* d_out, int out_size, void* d_ws, size_t ws_size,
                              hipStream_t stream) {
  const float* Q = (const float*)d_in[0];
  const float* K = (const float*)d_in[1];
  const float* V = (const float*)d_in[2];
  const int* lens = (const int*)d_in[3];

  float* ctx = (float*)d_out;                      // [B,Q,D]
  float* P = ctx + (size_t)NB * NQ * ND;           // [B,Q,K] weights region
  float* psum = (float*)d_ws;                      // [4][B][Q] partial row sums
  bf16_t* VT = (bf16_t*)((char*)d_ws + (size_t)4 * NB * NQ * sizeof(float));

  vt_kernel<<<dim3(64, 16), 256, 0, stream>>>(V, VT, lens);
  qk_kernel<<<dim3(64, 16), 256, 0, stream>>>(Q, K, P, psum, lens);
  pv_kernel<<<dim3(32, 16), 512, 0, stream>>>(P, VT, ctx, psum, lens);
}

// Round 2
// 311.442 us; speedup vs baseline: 1.1897x; 1.1897x over previous
//
#include <hip/hip_runtime.h>
#include <stdint.h>

typedef __bf16 bf16_t;
typedef bf16_t bf16x8 __attribute__((ext_vector_type(8)));
typedef float f32x4 __attribute__((ext_vector_type(4)));

#define NB 16
#define NQ 2048
#define NK 2048
#define ND 512
#define SCALE 0.04419417382415922f  // 1/sqrt(512)

typedef __attribute__((address_space(3))) uint32_t lds_u32;
typedef __attribute__((address_space(1))) const uint32_t glb_u32;

__device__ __forceinline__ float4 ld4(const float* p) { return *(const float4*)p; }

__device__ __forceinline__ f32x4 mfma16(bf16x8 a, bf16x8 b, f32x4 c) {
  return __builtin_amdgcn_mfma_f32_16x16x32_bf16(a, b, c, 0, 0, 0);
}

// ---------------------------------------------------------------------------
// Kernel P: Q,K fp32 [b][2048][512] -> bf16 tiles [b][rt/nt][kt][8KB].
// Tile layout is the LDS image qk wants: 128 rows x 4 chunks of 16B, with the
// chunk stored at slot = c ^ ((r>>1)&3)  (inverse-swizzled source so that
// linear global_load_lds + swizzled ds_read is an identity — rule #21).
// ---------------------------------------------------------------------------
__global__ __launch_bounds__(256) void qkprep_kernel(const float* __restrict__ Qf,
                                                     const float* __restrict__ Kf,
                                                     bf16_t* __restrict__ Qb,
                                                     bf16_t* __restrict__ Kb) {
  int x = blockIdx.x;  // rt*16 + kt
  int b = blockIdx.y;
  const float* src = blockIdx.z ? Kf : Qf;
  bf16_t* dst = blockIdx.z ? Kb : Qb;
  int rt = x >> 4, kt = x & 15;
  const float* s = src + ((size_t)b * 2048 + (size_t)rt * 128) * 512 + kt * 32;
  bf16_t* dtile = dst + (((size_t)b * 16 + rt) * 16 + kt) * 4096;
  int t = threadIdx.x;
#pragma unroll
  for (int i = 0; i < 2; ++i) {
    int d = i * 256 + t;           // dst chunk index 0..511
    int r = d >> 2, slot = d & 3;
    int c = slot ^ ((r >> 1) & 3); // source k-chunk
    const float* p = s + (size_t)r * 512 + c * 8;
    float4 v0 = ld4(p), v1 = ld4(p + 4);
    bf16x8 o;
    o[0] = (bf16_t)v0.x; o[1] = (bf16_t)v0.y; o[2] = (bf16_t)v0.z; o[3] = (bf16_t)v0.w;
    o[4] = (bf16_t)v1.x; o[5] = (bf16_t)v1.y; o[6] = (bf16_t)v1.z; o[7] = (bf16_t)v1.w;
    *(bf16x8*)(dtile + (size_t)d * 8) = o;
  }
}

// ---------------------------------------------------------------------------
// Kernel 0: V [B][K][D] fp32 -> VT bf16 tiles (LDS image for pv). Unchanged.
// ---------------------------------------------------------------------------
__global__ __launch_bounds__(256) void vt_kernel(const float* __restrict__ V,
                                                 bf16_t* __restrict__ VT,
                                                 const int* __restrict__ lens) {
  int kb = blockIdx.x, b = blockIdx.y;
  if (kb * 32 >= lens[b]) return;
  const float* vsrc = V + ((size_t)b * NK + kb * 32) * ND;
  bf16_t* dst = VT + ((size_t)(b * 64 + kb)) * (512 * 32);
  __shared__ alignas(16) bf16_t Ls[32][128];
  int t = threadIdx.x;
  for (int dbase = 0; dbase < ND; dbase += 128) {
#pragma unroll
    for (int i = 0; i < 4; ++i) {
      int p = i * 256 + t;
      int k = p >> 5, c4 = p & 31;
      float4 v = ld4(vsrc + (size_t)k * ND + dbase + c4 * 4);
      union { bf16_t h[4]; uint2 u; } pk;
      pk.h[0] = (bf16_t)v.x; pk.h[1] = (bf16_t)v.y;
      pk.h[2] = (bf16_t)v.z; pk.h[3] = (bf16_t)v.w;
      *(uint2*)(&Ls[k][c4 * 4]) = pk.u;
    }
    __syncthreads();
    int d = dbase + (t >> 1);
    int h = t & 1;
    int sr = d >> 1;
#pragma unroll
    for (int gg = 0; gg < 2; ++gg) {
      int g = h * 2 + gg;
      bf16x8 v;
#pragma unroll
      for (int j = 0; j < 8; ++j) v[j] = Ls[g * 8 + j][d - dbase];
      int slot = (((d & 1) << 2) | g) ^ (sr & 7);
      *(bf16x8*)(dst + ((size_t)sr * 8 + slot) * 8) = v;
    }
    __syncthreads();
  }
}

// ---------------------------------------------------------------------------
// Kernel 1 (rebuilt, m97 structure): per block (b, qt, nt) one 128x128 P tile.
// bf16 pre-swizzled inputs, global_load_lds staging (16B), BK=32, dbuf LDS,
// 16 MFMA + 8 ds_read_b128 per wave per k-step. Fused exp/mask/rowsum.
// ---------------------------------------------------------------------------
__global__ __launch_bounds__(256, 3) void qk_kernel(const bf16_t* __restrict__ Qb,
                                                    const bf16_t* __restrict__ Kb,
                                                    float* __restrict__ P,
                                                    float* __restrict__ psum,
                                                    const int* __restrict__ lens) {
  // XCD-bijective swizzle over 4096 blocks (4096 % 8 == 0)
  int bid = blockIdx.x;
  int swz = (bid & 7) * 512 + (bid >> 3);
  int b = swz >> 8;
  int tile = swz & 255;
  int qt = tile >> 4, nt = tile & 15;

  int len = lens[b];
  int q0 = qt * 128;
  int col0 = nt * 128;

  int t = threadIdx.x;
  float* prow = P + ((size_t)b * NQ + q0) * NK;

  if (col0 >= len) {  // fully masked tile: zeros, no staging
    float4 z = make_float4(0.f, 0.f, 0.f, 0.f);
#pragma unroll
    for (int i = 0; i < 16; ++i) {
      int p = i * 256 + t;
      int row = p >> 5, c4 = p & 31;
      *(float4*)(prow + (size_t)row * NK + col0 + c4 * 4) = z;
    }
    if (t < 128) psum[((size_t)b * 16 + nt) * NQ + q0 + t] = 0.f;
    return;
  }

  __shared__ alignas(16) bf16_t As[2][4096];
  __shared__ alignas(16) bf16_t Bs[2][4096];
  __shared__ float rsm[128];

  int lane = t & 63;
  int wid = t >> 6;
  int wm = wid >> 1, wn = wid & 1;
  int l15 = lane & 15, l4 = lane >> 4;

  const bf16_t* qtile = Qb + (((size_t)b * 16 + qt) * 16) * 4096;
  const bf16_t* ktile = Kb + (((size_t)b * 16 + nt) * 16) * 4096;

  f32x4 acc[4][4];
  f32x4 zz = {0.f, 0.f, 0.f, 0.f};
#pragma unroll
  for (int mi = 0; mi < 4; ++mi)
#pragma unroll
    for (int ni = 0; ni < 4; ++ni) acc[mi][ni] = zz;

  int eo = wid * 512 + lane * 8;  // element offset this lane stages

  auto stage = [&](int kt, int buf) {
    const bf16_t* qa = qtile + (size_t)kt * 4096;
    const bf16_t* ka = ktile + (size_t)kt * 4096;
    bf16_t* la = &As[buf][0];
    bf16_t* lb = &Bs[buf][0];
#pragma unroll
    for (int j = 0; j < 2; ++j) {
      __builtin_amdgcn_global_load_lds((glb_u32*)(qa + j * 2048 + eo),
                                       (lds_u32*)(la + j * 2048 + wid * 512), 16, 0, 0);
      __builtin_amdgcn_global_load_lds((glb_u32*)(ka + j * 2048 + eo),
                                       (lds_u32*)(lb + j * 2048 + wid * 512), 16, 0, 0);
    }
  };

  auto compute = [&](int buf) {
    bf16x8 af[4], bv[4];
#pragma unroll
    for (int mi = 0; mi < 4; ++mi) {
      int row = wm * 64 + mi * 16 + l15;
      int ch = row * 4 + (l4 ^ ((row >> 1) & 3));
      af[mi] = *(const bf16x8*)(&As[buf][ch * 8]);
    }
#pragma unroll
    for (int ni = 0; ni < 4; ++ni) {
      int row = wn * 64 + ni * 16 + l15;
      int ch = row * 4 + (l4 ^ ((row >> 1) & 3));
      bv[ni] = *(const bf16x8*)(&Bs[buf][ch * 8]);
    }
#pragma unroll
    for (int mi = 0; mi < 4; ++mi)
#pragma unroll
      for (int ni = 0; ni < 4; ++ni)
        acc[mi][ni] = mfma16(af[mi], bv[ni], acc[mi][ni]);
  };

  stage(0, 0);
  __syncthreads();
#pragma unroll 1
  for (int kt = 0; kt < 16; ++kt) {
    if (kt + 1 < 16) stage(kt + 1, (kt + 1) & 1);  // issue next while computing
    compute(kt & 1);
    __syncthreads();  // drains vmcnt + protects buf reuse
  }

  // epilogue: scale, mask, exp, rowsum, store unnormalized P
  float rsum[4][4];
#pragma unroll
  for (int mi = 0; mi < 4; ++mi)
#pragma unroll
    for (int r = 0; r < 4; ++r) rsum[mi][r] = 0.f;

#pragma unroll
  for (int mi = 0; mi < 4; ++mi) {
#pragma unroll
    for (int ni = 0; ni < 4; ++ni) {
      int col = col0 + wn * 64 + ni * 16 + l15;
      bool valid = col < len;
#pragma unroll
      for (int r = 0; r < 4; ++r) {
        float e = valid ? __expf(acc[mi][ni][r] * SCALE) : 0.f;
        rsum[mi][r] += e;
        prow[(size_t)(wm * 64 + mi * 16 + l4 * 4 + r) * NK + col] = e;
      }
    }
  }

  // reduce across the 16 col-lanes (l15), then across the two wn halves
#pragma unroll
  for (int off = 1; off < 16; off <<= 1)
#pragma unroll
    for (int mi = 0; mi < 4; ++mi)
#pragma unroll
      for (int r = 0; r < 4; ++r)
        rsum[mi][r] += __shfl_xor(rsum[mi][r], off, 64);

  if (wn == 0 && l15 == 0) {
#pragma unroll
    for (int mi = 0; mi < 4; ++mi)
#pragma unroll
      for (int r = 0; r < 4; ++r)
        rsm[wm * 64 + mi * 16 + l4 * 4 + r] = rsum[mi][r];
  }
  __syncthreads();
  if (wn == 1 && l15 == 0) {
#pragma unroll
    for (int mi = 0; mi < 4; ++mi)
#pragma unroll
      for (int r = 0; r < 4; ++r) {
        int row = wm * 64 + mi * 16 + l4 * 4 + r;
        psum[((size_t)b * 16 + nt) * NQ + q0 + row] = rsum[mi][r] + rsm[row];
      }
  }
}

// ---------------------------------------------------------------------------
// Kernel 2: context = Wnorm x V; normalizes P in-flight, writes W back and ctx.
// Unchanged except psum now has 16 nt-partials.
// ---------------------------------------------------------------------------
__global__ __launch_bounds__(512, 2) void pv_kernel(float* __restrict__ P,
                                                    const bf16_t* __restrict__ VT,
                                                    float* __restrict__ ctx,
                                                    const float* __restrict__ psum,
                                                    const int* __restrict__ lens) {
  int qt = blockIdx.x, b = blockIdx.y;
  int q0 = qt * 64;
  int len = lens[b];
  int nsteps = (len + 31) >> 5;

  __shared__ alignas(16) bf16_t Ps[2][64 * 32];
  __shared__ alignas(16) bf16_t Vs[2][512 * 32];
  __shared__ float rcp[64];

  int t = threadIdx.x;
  if (t < 64) {
    float s = 0.f;
#pragma unroll
    for (int i = 0; i < 16; ++i) s += psum[((size_t)b * 16 + i) * NQ + q0 + t];
    rcp[t] = 1.0f / s;
  }
  __syncthreads();

  float* prow = P + ((size_t)b * NQ + q0) * NK;
  const bf16_t* vtb = VT + ((size_t)b * 64) * (512 * 32);

  int lane = t & 63, wid = t >> 6;
  int l15 = lane & 15, l4 = lane >> 4;

  f32x4 acc[4][4];
  f32x4 zz = {0.f, 0.f, 0.f, 0.f};
#pragma unroll
  for (int mi = 0; mi < 4; ++mi)
#pragma unroll
    for (int ni = 0; ni < 4; ++ni) acc[mi][ni] = zz;

  int srow = t >> 3, sc4 = t & 7;
  float rr = rcp[srow];

  float4 pld;
  bf16x8 vld[4];

  auto stage_load = [&](int ks) {
    pld = ld4(prow + (size_t)srow * NK + ks * 32 + sc4 * 4);
    const bf16_t* src = vtb + (size_t)ks * (512 * 32);
#pragma unroll
    for (int i = 0; i < 4; ++i)
      vld[i] = *(const bf16x8*)(src + ((size_t)i * 512 + t) * 8);
  };
  auto stage_finish = [&](int ks, int buf) {
    float4 w;
    w.x = pld.x * rr; w.y = pld.y * rr; w.z = pld.z * rr; w.w = pld.w * rr;
    *(float4*)(prow + (size_t)srow * NK + ks * 32 + sc4 * 4) = w;  // normalized W
    int sr = srow >> 1;
    int slot = (((srow & 1) << 2) | (sc4 >> 1)) ^ (sr & 7);
    union { bf16_t h[4]; uint2 u; } pk;
    pk.h[0] = (bf16_t)w.x; pk.h[1] = (bf16_t)w.y;
    pk.h[2] = (bf16_t)w.z; pk.h[3] = (bf16_t)w.w;
    *(uint2*)(&Ps[buf][((size_t)sr * 8 + slot) * 8 + (sc4 & 1) * 4]) = pk.u;
#pragma unroll
    for (int i = 0; i < 4; ++i)
      *(bf16x8*)(&Vs[buf][((size_t)i * 512 + t) * 8]) = vld[i];
  };
  auto compute = [&](int cur) {
    bf16x8 af[4], bv[4];
#pragma unroll
    for (int mi = 0; mi < 4; ++mi) {
      int row = mi * 16 + l15;
      af[mi] = *(const bf16x8*)(&Ps[cur][((row >> 1) * 8 + ((((row & 1) << 2) | l4) ^ ((row >> 1) & 7))) * 8]);
    }
#pragma unroll
    for (int ni = 0; ni < 4; ++ni) {
      int d = wid * 64 + ni * 16 + l15;
      bv[ni] = *(const bf16x8*)(&Vs[cur][((d >> 1) * 8 + ((((d & 1) << 2) | l4) ^ ((d >> 1) & 7))) * 8]);
    }
#pragma unroll
    for (int mi = 0; mi < 4; ++mi)
#pragma unroll
      for (int ni = 0; ni < 4; ++ni)
        acc[mi][ni] = mfma16(af[mi], bv[ni], acc[mi][ni]);
  };

  stage_load(0);
  stage_finish(0, 0);
  __syncthreads();
  for (int ks = 0; ks < nsteps; ++ks) {
    int cur = ks & 1;
    if (ks + 1 < nsteps) stage_load(ks + 1);
    compute(cur);
    if (ks + 1 < nsteps) stage_finish(ks + 1, cur ^ 1);
    __syncthreads();
  }

  float* crow = ctx + ((size_t)b * NQ + q0) * ND + wid * 64;
#pragma unroll
  for (int mi = 0; mi < 4; ++mi)
#pragma unroll
    for (int ni = 0; ni < 4; ++ni)
#pragma unroll
      for (int r = 0; r < 4; ++r)
        crow[(size_t)(mi * 16 + l4 * 4 + r) * ND + ni * 16 + l15] = acc[mi][ni][r];
}

// ---------------------------------------------------------------------------
extern "C" void kernel_launch(void* const* d_in, const int* in_sizes, int n_in,
                              void* d_out, int out_size, void* d_ws, size_t ws_size,
                              hipStream_t stream) {
  const float* Q = (const float*)d_in[0];
  const float* K = (const float*)d_in[1];
  const float* V = (const float*)d_in[2];
  const int* lens = (const int*)d_in[3];

  float* ctx = (float*)d_out;             // [B,Q,D]
  float* P = ctx + (size_t)NB * NQ * ND;  // [B,Q,K] weights region

  // ws layout: psum [B][16][NQ] f32 (2 MB) | Qb 32 MB | Kb 32 MB | VT 32 MB
  float* psum = (float*)d_ws;
  char* base = (char*)d_ws + (size_t)NB * 16 * NQ * sizeof(float);
  bf16_t* Qb = (bf16_t*)base;
  bf16_t* Kb = (bf16_t*)(base + (size_t)NB * NQ * ND * 2);
  bf16_t* VT = (bf16_t*)(base + (size_t)2 * NB * NQ * ND * 2);

  qkprep_kernel<<<dim3(256, 16, 2), 256, 0, stream>>>(Q, K, Qb, Kb);
  vt_kernel<<<dim3(64, 16), 256, 0, stream>>>(V, VT, lens);
  qk_kernel<<<dim3(4096), 256, 0, stream>>>(Qb, Kb, P, psum, lens);
  pv_kernel<<<dim3(32, 16), 512, 0, stream>>>(P, VT, ctx, psum, lens);
}

// Round 3
// 310.822 us; speedup vs baseline: 1.1921x; 1.0020x over previous
//
#include <hip/hip_runtime.h>
#include <stdint.h>

typedef __bf16 bf16_t;
typedef bf16_t bf16x8 __attribute__((ext_vector_type(8)));
typedef bf16_t bf16x4_t __attribute__((ext_vector_type(4)));
typedef float f32x4 __attribute__((ext_vector_type(4)));

#define NB 16
#define NQ 2048
#define NK 2048
#define ND 512
#define SCALE 0.04419417382415922f  // 1/sqrt(512)

typedef __attribute__((address_space(3))) uint32_t lds_u32;
typedef __attribute__((address_space(1))) const uint32_t glb_u32;

__device__ __forceinline__ float4 ld4(const float* p) { return *(const float4*)p; }

__device__ __forceinline__ f32x4 mfma16(bf16x8 a, bf16x8 b, f32x4 c) {
  return __builtin_amdgcn_mfma_f32_16x16x32_bf16(a, b, c, 0, 0, 0);
}

// ---------------------------------------------------------------------------
// Kernel P: Q,K fp32 [b][2048][512] -> bf16 tiles [b][rt/nt][kt][8KB], stored
// inverse-swizzled so qk's linear global_load_lds + swizzled ds_read works.
// ---------------------------------------------------------------------------
__global__ __launch_bounds__(256) void qkprep_kernel(const float* __restrict__ Qf,
                                                     const float* __restrict__ Kf,
                                                     bf16_t* __restrict__ Qb,
                                                     bf16_t* __restrict__ Kb) {
  int x = blockIdx.x;  // rt*16 + kt
  int b = blockIdx.y;
  const float* src = blockIdx.z ? Kf : Qf;
  bf16_t* dst = blockIdx.z ? Kb : Qb;
  int rt = x >> 4, kt = x & 15;
  const float* s = src + ((size_t)b * 2048 + (size_t)rt * 128) * 512 + kt * 32;
  bf16_t* dtile = dst + (((size_t)b * 16 + rt) * 16 + kt) * 4096;
  int t = threadIdx.x;
#pragma unroll
  for (int i = 0; i < 2; ++i) {
    int d = i * 256 + t;           // dst chunk index 0..511
    int r = d >> 2, slot = d & 3;
    int c = slot ^ ((r >> 1) & 3); // source k-chunk
    const float* p = s + (size_t)r * 512 + c * 8;
    float4 v0 = ld4(p), v1 = ld4(p + 4);
    bf16x8 o;
    o[0] = (bf16_t)v0.x; o[1] = (bf16_t)v0.y; o[2] = (bf16_t)v0.z; o[3] = (bf16_t)v0.w;
    o[4] = (bf16_t)v1.x; o[5] = (bf16_t)v1.y; o[6] = (bf16_t)v1.z; o[7] = (bf16_t)v1.w;
    *(bf16x8*)(dtile + (size_t)d * 8) = o;
  }
}

// ---------------------------------------------------------------------------
// Kernel 0: V [B][K][D] fp32 -> VT bf16 tiles (LDS image for pv). Unchanged.
// ---------------------------------------------------------------------------
__global__ __launch_bounds__(256) void vt_kernel(const float* __restrict__ V,
                                                 bf16_t* __restrict__ VT,
                                                 const int* __restrict__ lens) {
  int kb = blockIdx.x, b = blockIdx.y;
  if (kb * 32 >= lens[b]) return;
  const float* vsrc = V + ((size_t)b * NK + kb * 32) * ND;
  bf16_t* dst = VT + ((size_t)(b * 64 + kb)) * (512 * 32);
  __shared__ alignas(16) bf16_t Ls[32][128];
  int t = threadIdx.x;
  for (int dbase = 0; dbase < ND; dbase += 128) {
#pragma unroll
    for (int i = 0; i < 4; ++i) {
      int p = i * 256 + t;
      int k = p >> 5, c4 = p & 31;
      float4 v = ld4(vsrc + (size_t)k * ND + dbase + c4 * 4);
      union { bf16_t h[4]; uint2 u; } pk;
      pk.h[0] = (bf16_t)v.x; pk.h[1] = (bf16_t)v.y;
      pk.h[2] = (bf16_t)v.z; pk.h[3] = (bf16_t)v.w;
      *(uint2*)(&Ls[k][c4 * 4]) = pk.u;
    }
    __syncthreads();
    int d = dbase + (t >> 1);
    int h = t & 1;
    int sr = d >> 1;
#pragma unroll
    for (int gg = 0; gg < 2; ++gg) {
      int g = h * 2 + gg;
      bf16x8 v;
#pragma unroll
      for (int j = 0; j < 8; ++j) v[j] = Ls[g * 8 + j][d - dbase];
      int slot = (((d & 1) << 2) | g) ^ (sr & 7);
      *(bf16x8*)(dst + ((size_t)sr * 8 + slot) * 8) = v;
    }
    __syncthreads();
  }
}

// ---------------------------------------------------------------------------
// Kernel 1 (m97 structure): per block (b, qt, nt) one 128x128 exp(S) tile.
// Writes UNNORMALIZED bf16 P into the byte range [4096,8192) of each fp32 W
// output row (aliased scratch; pv later overwrites the row with fp32 W).
// Fully-masked tiles: no work, no writes. Fused exp/mask/rowsum.
// ---------------------------------------------------------------------------
__global__ __launch_bounds__(256, 3) void qk_kernel(const bf16_t* __restrict__ Qb,
                                                    const bf16_t* __restrict__ Kb,
                                                    float* __restrict__ P,
                                                    float* __restrict__ psum,
                                                    const int* __restrict__ lens) {
  // XCD-bijective swizzle over 4096 blocks (4096 % 8 == 0)
  int bid = blockIdx.x;
  int swz = (bid & 7) * 512 + (bid >> 3);
  int b = swz >> 8;
  int tile = swz & 255;
  int qt = tile >> 4, nt = tile & 15;

  int len = lens[b];
  int q0 = qt * 128;
  int col0 = nt * 128;
  if (col0 >= len) return;  // fully masked: pv zero-fills W, psum never read

  __shared__ alignas(16) bf16_t As[2][4096];
  __shared__ alignas(16) bf16_t Bs[2][4096];
  __shared__ float rsm[128];

  int t = threadIdx.x;
  int lane = t & 63;
  int wid = t >> 6;
  int wm = wid >> 1, wn = wid & 1;
  int l15 = lane & 15, l4 = lane >> 4;

  float* prow = P + ((size_t)b * NQ + q0) * NK;
  const bf16_t* qtile = Qb + (((size_t)b * 16 + qt) * 16) * 4096;
  const bf16_t* ktile = Kb + (((size_t)b * 16 + nt) * 16) * 4096;

  f32x4 acc[4][4];
  f32x4 zz = {0.f, 0.f, 0.f, 0.f};
#pragma unroll
  for (int mi = 0; mi < 4; ++mi)
#pragma unroll
    for (int ni = 0; ni < 4; ++ni) acc[mi][ni] = zz;

  int eo = wid * 512 + lane * 8;  // element offset this lane stages

  auto stage = [&](int kt, int buf) {
    const bf16_t* qa = qtile + (size_t)kt * 4096;
    const bf16_t* ka = ktile + (size_t)kt * 4096;
    bf16_t* la = &As[buf][0];
    bf16_t* lb = &Bs[buf][0];
#pragma unroll
    for (int j = 0; j < 2; ++j) {
      __builtin_amdgcn_global_load_lds((glb_u32*)(qa + j * 2048 + eo),
                                       (lds_u32*)(la + j * 2048 + wid * 512), 16, 0, 0);
      __builtin_amdgcn_global_load_lds((glb_u32*)(ka + j * 2048 + eo),
                                       (lds_u32*)(lb + j * 2048 + wid * 512), 16, 0, 0);
    }
  };

  auto compute = [&](int buf) {
    bf16x8 af[4], bv[4];
#pragma unroll
    for (int mi = 0; mi < 4; ++mi) {
      int row = wm * 64 + mi * 16 + l15;
      int ch = row * 4 + (l4 ^ ((row >> 1) & 3));
      af[mi] = *(const bf16x8*)(&As[buf][ch * 8]);
    }
#pragma unroll
    for (int ni = 0; ni < 4; ++ni) {
      int row = wn * 64 + ni * 16 + l15;
      int ch = row * 4 + (l4 ^ ((row >> 1) & 3));
      bv[ni] = *(const bf16x8*)(&Bs[buf][ch * 8]);
    }
#pragma unroll
    for (int mi = 0; mi < 4; ++mi)
#pragma unroll
      for (int ni = 0; ni < 4; ++ni)
        acc[mi][ni] = mfma16(af[mi], bv[ni], acc[mi][ni]);
  };

  stage(0, 0);
  __syncthreads();
#pragma unroll 1
  for (int kt = 0; kt < 16; ++kt) {
    if (kt + 1 < 16) stage(kt + 1, (kt + 1) & 1);
    compute(kt & 1);
    __syncthreads();
  }

  // epilogue: scale, mask, exp, rowsum over bf16-rounded e, store bf16 Pu
  float rsum[4][4];
#pragma unroll
  for (int mi = 0; mi < 4; ++mi)
#pragma unroll
    for (int r = 0; r < 4; ++r) rsum[mi][r] = 0.f;

#pragma unroll
  for (int mi = 0; mi < 4; ++mi) {
#pragma unroll
    for (int ni = 0; ni < 4; ++ni) {
      int col = col0 + wn * 64 + ni * 16 + l15;
      bool valid = col < len;
#pragma unroll
      for (int r = 0; r < 4; ++r) {
        float e = valid ? __expf(acc[mi][ni][r] * SCALE) : 0.f;
        bf16_t eb = (bf16_t)e;
        rsum[mi][r] += (float)eb;
        bf16_t* purow =
            (bf16_t*)(prow + (size_t)(wm * 64 + mi * 16 + l4 * 4 + r) * NK) + 2048;
        purow[col] = eb;
      }
    }
  }

#pragma unroll
  for (int off = 1; off < 16; off <<= 1)
#pragma unroll
    for (int mi = 0; mi < 4; ++mi)
#pragma unroll
      for (int r = 0; r < 4; ++r)
        rsum[mi][r] += __shfl_xor(rsum[mi][r], off, 64);

  if (wn == 0 && l15 == 0) {
#pragma unroll
    for (int mi = 0; mi < 4; ++mi)
#pragma unroll
      for (int r = 0; r < 4; ++r)
        rsm[wm * 64 + mi * 16 + l4 * 4 + r] = rsum[mi][r];
  }
  __syncthreads();
  if (wn == 1 && l15 == 0) {
#pragma unroll
    for (int mi = 0; mi < 4; ++mi)
#pragma unroll
      for (int r = 0; r < 4; ++r) {
        int row = wm * 64 + mi * 16 + l4 * 4 + r;
        psum[((size_t)b * 16 + nt) * NQ + q0 + row] = rsum[mi][r] + rsm[row];
      }
  }
}

// ---------------------------------------------------------------------------
// Kernel 2: context = Wnorm x V. Reads bf16 Pu from W-row bytes [4096,8192),
// normalizes in-flight, writes fp32 W over bytes [ks*128..) of the same row
// (write-front provably behind read-front; single ks==62/nsteps==64 overlap
// fenced with a barrier), zero-fills the masked W tail after the loop.
// ---------------------------------------------------------------------------
__global__ __launch_bounds__(512, 2) void pv_kernel(float* __restrict__ P,
                                                    const bf16_t* __restrict__ VT,
                                                    float* __restrict__ ctx,
                                                    const float* __restrict__ psum,
                                                    const int* __restrict__ lens) {
  int qt = blockIdx.x, b = blockIdx.y;
  int q0 = qt * 64;
  int len = lens[b];
  int nsteps = (len + 31) >> 5;
  int nvalid = (len + 127) >> 7;  // valid nt tiles in psum

  __shared__ alignas(16) bf16_t Ps[2][64 * 32];
  __shared__ alignas(16) bf16_t Vs[2][512 * 32];
  __shared__ float rcp[64];

  int t = threadIdx.x;
  if (t < 64) {
    float s = 0.f;
    for (int i = 0; i < nvalid; ++i) s += psum[((size_t)b * 16 + i) * NQ + q0 + t];
    rcp[t] = 1.0f / s;
  }
  __syncthreads();

  float* prow = P + ((size_t)b * NQ + q0) * NK;
  const bf16_t* vtb = VT + ((size_t)b * 64) * (512 * 32);

  int lane = t & 63, wid = t >> 6;
  int l15 = lane & 15, l4 = lane >> 4;

  f32x4 acc[4][4];
  f32x4 zz = {0.f, 0.f, 0.f, 0.f};
#pragma unroll
  for (int mi = 0; mi < 4; ++mi)
#pragma unroll
    for (int ni = 0; ni < 4; ++ni) acc[mi][ni] = zz;

  int srow = t >> 3, sc4 = t & 7;
  float rr = rcp[srow];
  const bf16_t* purow = (const bf16_t*)(prow + (size_t)srow * NK) + 2048;

  bf16x4_t pld;
  bf16x8 vld[4];

  auto stage_load = [&](int ks) {
    pld = *(const bf16x4_t*)(purow + ks * 32 + sc4 * 4);
    const bf16_t* src = vtb + (size_t)ks * (512 * 32);
#pragma unroll
    for (int i = 0; i < 4; ++i)
      vld[i] = *(const bf16x8*)(src + ((size_t)i * 512 + t) * 8);
  };
  auto stage_finish = [&](int ks, int buf) {
    float4 w;
    w.x = (float)pld[0] * rr; w.y = (float)pld[1] * rr;
    w.z = (float)pld[2] * rr; w.w = (float)pld[3] * rr;
    *(float4*)(prow + (size_t)srow * NK + ks * 32 + sc4 * 4) = w;  // normalized W
    int sr = srow >> 1;
    int slot = (((srow & 1) << 2) | (sc4 >> 1)) ^ (sr & 7);
    union { bf16_t h[4]; uint2 u; } pk;
    pk.h[0] = (bf16_t)w.x; pk.h[1] = (bf16_t)w.y;
    pk.h[2] = (bf16_t)w.z; pk.h[3] = (bf16_t)w.w;
    *(uint2*)(&Ps[buf][((size_t)sr * 8 + slot) * 8 + (sc4 & 1) * 4]) = pk.u;
#pragma unroll
    for (int i = 0; i < 4; ++i)
      *(bf16x8*)(&Vs[buf][((size_t)i * 512 + t) * 8]) = vld[i];
  };
  auto compute = [&](int cur) {
    bf16x8 af[4], bv[4];
#pragma unroll
    for (int mi = 0; mi < 4; ++mi) {
      int row = mi * 16 + l15;
      af[mi] = *(const bf16x8*)(&Ps[cur][((row >> 1) * 8 + ((((row & 1) << 2) | l4) ^ ((row >> 1) & 7))) * 8]);
    }
#pragma unroll
    for (int ni = 0; ni < 4; ++ni) {
      int d = wid * 64 + ni * 16 + l15;
      bv[ni] = *(const bf16x8*)(&Vs[cur][((d >> 1) * 8 + ((((d & 1) << 2) | l4) ^ ((d >> 1) & 7))) * 8]);
    }
#pragma unroll
    for (int mi = 0; mi < 4; ++mi)
#pragma unroll
      for (int ni = 0; ni < 4; ++ni)
        acc[mi][ni] = mfma16(af[mi], bv[ni], acc[mi][ni]);
  };

  stage_load(0);
  stage_finish(0, 0);
  __syncthreads();
  for (int ks = 0; ks < nsteps; ++ks) {
    int cur = ks & 1;
    if (ks + 1 < nsteps) stage_load(ks + 1);
    compute(cur);
    if (ks == 62 && nsteps == 64) __syncthreads();  // fence ks=63 read/write alias
    if (ks + 1 < nsteps) stage_finish(ks + 1, cur ^ 1);
    __syncthreads();
  }

  // zero-fill masked W tail (all Pu reads completed at the final barrier)
  {
    float4 z = make_float4(0.f, 0.f, 0.f, 0.f);
    int tr = t >> 3, tc = t & 7;
    for (int c = nsteps * 32 + tc * 4; c < NK; c += 32)
      *(float4*)(prow + (size_t)tr * NK + c) = z;
  }

  float* crow = ctx + ((size_t)b * NQ + q0) * ND + wid * 64;
#pragma unroll
  for (int mi = 0; mi < 4; ++mi)
#pragma unroll
    for (int ni = 0; ni < 4; ++ni)
#pragma unroll
      for (int r = 0; r < 4; ++r)
        crow[(size_t)(mi * 16 + l4 * 4 + r) * ND + ni * 16 + l15] = acc[mi][ni][r];
}

// ---------------------------------------------------------------------------
extern "C" void kernel_launch(void* const* d_in, const int* in_sizes, int n_in,
                              void* d_out, int out_size, void* d_ws, size_t ws_size,
                              hipStream_t stream) {
  const float* Q = (const float*)d_in[0];
  const float* K = (const float*)d_in[1];
  const float* V = (const float*)d_in[2];
  const int* lens = (const int*)d_in[3];

  float* ctx = (float*)d_out;             // [B,Q,D]
  float* P = ctx + (size_t)NB * NQ * ND;  // [B,Q,K] weights region

  // ws layout: psum [B][16][NQ] f32 (2 MB) | Qb 32 MB | Kb 32 MB | VT 32 MB
  float* psum = (float*)d_ws;
  char* base = (char*)d_ws + (size_t)NB * 16 * NQ * sizeof(float);
  bf16_t* Qb = (bf16_t*)base;
  bf16_t* Kb = (bf16_t*)(base + (size_t)NB * NQ * ND * 2);
  bf16_t* VT = (bf16_t*)(base + (size_t)2 * NB * NQ * ND * 2);

  qkprep_kernel<<<dim3(256, 16, 2), 256, 0, stream>>>(Q, K, Qb, Kb);
  vt_kernel<<<dim3(64, 16), 256, 0, stream>>>(V, VT, lens);
  qk_kernel<<<dim3(4096), 256, 0, stream>>>(Qb, Kb, P, psum, lens);
  pv_kernel<<<dim3(32, 16), 512, 0, stream>>>(P, VT, ctx, psum, lens);
}

// Round 4
// 284.147 us; speedup vs baseline: 1.3040x; 1.0939x over previous
//
#include <hip/hip_runtime.h>
#include <stdint.h>

typedef __bf16 bf16_t;
typedef bf16_t bf16x8 __attribute__((ext_vector_type(8)));
typedef bf16_t bf16x4_t __attribute__((ext_vector_type(4)));
typedef float f32x4 __attribute__((ext_vector_type(4)));

#define NB 16
#define NQ 2048
#define NK 2048
#define ND 512
#define SCALE 0.04419417382415922f  // 1/sqrt(512)

typedef __attribute__((address_space(3))) uint32_t lds_u32;
typedef __attribute__((address_space(1))) const uint32_t glb_u32;

__device__ __forceinline__ float4 ld4(const float* p) { return *(const float4*)p; }

__device__ __forceinline__ f32x4 mfma16(bf16x8 a, bf16x8 b, f32x4 c) {
  return __builtin_amdgcn_mfma_f32_16x16x32_bf16(a, b, c, 0, 0, 0);
}

// ---------------------------------------------------------------------------
// Kernel P (merged prep): z=0 Q->Qb, z=1 K->Kb (inverse-swizzled bf16 tiles
// for qk's global_load_lds), z=2 V->VT (LDS-image bf16 tiles for pv).
// ---------------------------------------------------------------------------
__global__ __launch_bounds__(256) void prep_kernel(const float* __restrict__ Qf,
                                                   const float* __restrict__ Kf,
                                                   const float* __restrict__ Vf,
                                                   bf16_t* __restrict__ Qb,
                                                   bf16_t* __restrict__ Kb,
                                                   bf16_t* __restrict__ VT,
                                                   const int* __restrict__ lens) {
  int x = blockIdx.x;
  int b = blockIdx.y;
  int z = blockIdx.z;
  int t = threadIdx.x;

  if (z == 2) {  // V transpose quarter: kb = x>>2, d-range quarter = x&3
    int kb = x >> 2, dq = (x & 3) * 128;
    if (kb * 32 >= lens[b]) return;
    const float* vsrc = Vf + ((size_t)b * NK + kb * 32) * ND;
    bf16_t* dst = VT + ((size_t)(b * 64 + kb)) * (512 * 32);
    __shared__ alignas(16) bf16_t Ls[32][128];
#pragma unroll
    for (int i = 0; i < 4; ++i) {
      int p = i * 256 + t;
      int k = p >> 5, c4 = p & 31;
      float4 v = ld4(vsrc + (size_t)k * ND + dq + c4 * 4);
      union { bf16_t h[4]; uint2 u; } pk;
      pk.h[0] = (bf16_t)v.x; pk.h[1] = (bf16_t)v.y;
      pk.h[2] = (bf16_t)v.z; pk.h[3] = (bf16_t)v.w;
      *(uint2*)(&Ls[k][c4 * 4]) = pk.u;
    }
    __syncthreads();
    int d = dq + (t >> 1);
    int h = t & 1;
    int sr = d >> 1;
#pragma unroll
    for (int gg = 0; gg < 2; ++gg) {
      int g = h * 2 + gg;
      bf16x8 v;
#pragma unroll
      for (int j = 0; j < 8; ++j) v[j] = Ls[g * 8 + j][d - dq];
      int slot = (((d & 1) << 2) | g) ^ (sr & 7);
      *(bf16x8*)(dst + ((size_t)sr * 8 + slot) * 8) = v;
    }
    return;
  }

  // z = 0/1: Q/K tile prep
  const float* src = z ? Kf : Qf;
  bf16_t* dst = z ? Kb : Qb;
  int rt = x >> 4, kt = x & 15;
  const float* s = src + ((size_t)b * 2048 + (size_t)rt * 128) * 512 + kt * 32;
  bf16_t* dtile = dst + (((size_t)b * 16 + rt) * 16 + kt) * 4096;
#pragma unroll
  for (int i = 0; i < 2; ++i) {
    int d = i * 256 + t;           // dst chunk index 0..511
    int r = d >> 2, slot = d & 3;
    int c = slot ^ ((r >> 1) & 3); // source k-chunk
    const float* p = s + (size_t)r * 512 + c * 8;
    float4 v0 = ld4(p), v1 = ld4(p + 4);
    bf16x8 o;
    o[0] = (bf16_t)v0.x; o[1] = (bf16_t)v0.y; o[2] = (bf16_t)v0.z; o[3] = (bf16_t)v0.w;
    o[4] = (bf16_t)v1.x; o[5] = (bf16_t)v1.y; o[6] = (bf16_t)v1.z; o[7] = (bf16_t)v1.w;
    *(bf16x8*)(dtile + (size_t)d * 8) = o;
  }
}

// ---------------------------------------------------------------------------
// Kernel 1 (m97 structure, unchanged from round 3): per block (b, qt, nt) one
// 128x128 exp(S) tile. Writes UNNORMALIZED bf16 Pu into bytes [4096,8192) of
// each fp32 W row. Masked tiles: early-out. Fused exp/mask/rowsum -> psum.
// ---------------------------------------------------------------------------
__global__ __launch_bounds__(256, 3) void qk_kernel(const bf16_t* __restrict__ Qb,
                                                    const bf16_t* __restrict__ Kb,
                                                    float* __restrict__ P,
                                                    float* __restrict__ psum,
                                                    const int* __restrict__ lens) {
  int bid = blockIdx.x;
  int swz = (bid & 7) * 512 + (bid >> 3);
  int b = swz >> 8;
  int tile = swz & 255;
  int qt = tile >> 4, nt = tile & 15;

  int len = lens[b];
  int q0 = qt * 128;
  int col0 = nt * 128;
  if (col0 >= len) return;

  __shared__ alignas(16) bf16_t As[2][4096];
  __shared__ alignas(16) bf16_t Bs[2][4096];
  __shared__ float rsm[128];

  int t = threadIdx.x;
  int lane = t & 63;
  int wid = t >> 6;
  int wm = wid >> 1, wn = wid & 1;
  int l15 = lane & 15, l4 = lane >> 4;

  float* prow = P + ((size_t)b * NQ + q0) * NK;
  const bf16_t* qtile = Qb + (((size_t)b * 16 + qt) * 16) * 4096;
  const bf16_t* ktile = Kb + (((size_t)b * 16 + nt) * 16) * 4096;

  f32x4 acc[4][4];
  f32x4 zz = {0.f, 0.f, 0.f, 0.f};
#pragma unroll
  for (int mi = 0; mi < 4; ++mi)
#pragma unroll
    for (int ni = 0; ni < 4; ++ni) acc[mi][ni] = zz;

  int eo = wid * 512 + lane * 8;

  auto stage = [&](int kt2, int buf) {
    const bf16_t* qa = qtile + (size_t)kt2 * 4096;
    const bf16_t* ka = ktile + (size_t)kt2 * 4096;
    bf16_t* la = &As[buf][0];
    bf16_t* lb = &Bs[buf][0];
#pragma unroll
    for (int j = 0; j < 2; ++j) {
      __builtin_amdgcn_global_load_lds((glb_u32*)(qa + j * 2048 + eo),
                                       (lds_u32*)(la + j * 2048 + wid * 512), 16, 0, 0);
      __builtin_amdgcn_global_load_lds((glb_u32*)(ka + j * 2048 + eo),
                                       (lds_u32*)(lb + j * 2048 + wid * 512), 16, 0, 0);
    }
  };

  auto compute = [&](int buf) {
    bf16x8 af[4], bv[4];
#pragma unroll
    for (int mi = 0; mi < 4; ++mi) {
      int row = wm * 64 + mi * 16 + l15;
      int ch = row * 4 + (l4 ^ ((row >> 1) & 3));
      af[mi] = *(const bf16x8*)(&As[buf][ch * 8]);
    }
#pragma unroll
    for (int ni = 0; ni < 4; ++ni) {
      int row = wn * 64 + ni * 16 + l15;
      int ch = row * 4 + (l4 ^ ((row >> 1) & 3));
      bv[ni] = *(const bf16x8*)(&Bs[buf][ch * 8]);
    }
#pragma unroll
    for (int mi = 0; mi < 4; ++mi)
#pragma unroll
      for (int ni = 0; ni < 4; ++ni)
        acc[mi][ni] = mfma16(af[mi], bv[ni], acc[mi][ni]);
  };

  stage(0, 0);
  __syncthreads();
#pragma unroll 1
  for (int kt2 = 0; kt2 < 16; ++kt2) {
    if (kt2 + 1 < 16) stage(kt2 + 1, (kt2 + 1) & 1);
    compute(kt2 & 1);
    __syncthreads();
  }

  float rsum[4][4];
#pragma unroll
  for (int mi = 0; mi < 4; ++mi)
#pragma unroll
    for (int r = 0; r < 4; ++r) rsum[mi][r] = 0.f;

#pragma unroll
  for (int mi = 0; mi < 4; ++mi) {
#pragma unroll
    for (int ni = 0; ni < 4; ++ni) {
      int col = col0 + wn * 64 + ni * 16 + l15;
      bool valid = col < len;
#pragma unroll
      for (int r = 0; r < 4; ++r) {
        float e = valid ? __expf(acc[mi][ni][r] * SCALE) : 0.f;
        bf16_t eb = (bf16_t)e;
        rsum[mi][r] += (float)eb;
        bf16_t* purow =
            (bf16_t*)(prow + (size_t)(wm * 64 + mi * 16 + l4 * 4 + r) * NK) + 2048;
        purow[col] = eb;
      }
    }
  }

#pragma unroll
  for (int off = 1; off < 16; off <<= 1)
#pragma unroll
    for (int mi = 0; mi < 4; ++mi)
#pragma unroll
      for (int r = 0; r < 4; ++r)
        rsum[mi][r] += __shfl_xor(rsum[mi][r], off, 64);

  if (wn == 0 && l15 == 0) {
#pragma unroll
    for (int mi = 0; mi < 4; ++mi)
#pragma unroll
      for (int r = 0; r < 4; ++r)
        rsm[wm * 64 + mi * 16 + l4 * 4 + r] = rsum[mi][r];
  }
  __syncthreads();
  if (wn == 1 && l15 == 0) {
#pragma unroll
    for (int mi = 0; mi < 4; ++mi)
#pragma unroll
      for (int r = 0; r < 4; ++r) {
        int row = wm * 64 + mi * 16 + l4 * 4 + r;
        psum[((size_t)b * 16 + nt) * NQ + q0 + row] = rsum[mi][r] + rsm[row];
      }
  }
}

// ---------------------------------------------------------------------------
// Kernel 2 (rebuilt): context = Wnorm x V. P (shared by all 8 waves) staged
// through an 8KB LDS dbuf; V fragments (wave-private, zero reuse) read
// DIRECTLY from L2-resident VT — no V LDS staging. Normalizes P in-flight,
// writes fp32 W + zero tail + ctx. b = bid&15 mixes batch lengths per CU.
// ---------------------------------------------------------------------------
__global__ __launch_bounds__(512, 4) void pv_kernel(float* __restrict__ P,
                                                    const bf16_t* __restrict__ VT,
                                                    float* __restrict__ ctx,
                                                    const float* __restrict__ psum,
                                                    const int* __restrict__ lens) {
  int bid = blockIdx.x;
  int b = bid & 15, qt = bid >> 4;
  int q0 = qt * 64;
  int len = lens[b];
  int nsteps = (len + 31) >> 5;
  int nvalid = (len + 127) >> 7;

  __shared__ alignas(16) bf16_t Ps[2][64 * 32];
  __shared__ float rcp[64];

  int t = threadIdx.x;
  if (t < 64) {
    float s = 0.f;
    for (int i = 0; i < nvalid; ++i) s += psum[((size_t)b * 16 + i) * NQ + q0 + t];
    rcp[t] = 1.0f / s;
  }
  __syncthreads();

  float* prow = P + ((size_t)b * NQ + q0) * NK;
  const bf16_t* vtb = VT + ((size_t)b * 64) * (512 * 32);

  int lane = t & 63, wid = t >> 6;
  int l15 = lane & 15, l4 = lane >> 4;

  f32x4 acc[4][4];
  f32x4 zz = {0.f, 0.f, 0.f, 0.f};
#pragma unroll
  for (int mi = 0; mi < 4; ++mi)
#pragma unroll
    for (int ni = 0; ni < 4; ++ni) acc[mi][ni] = zz;

  int srow = t >> 3, sc4 = t & 7;
  float rr = rcp[srow];
  const bf16_t* purow = (const bf16_t*)(prow + (size_t)srow * NK) + 2048;

  // precompute V-fragment chunk offsets for this lane (4 per wave)
  int vchunk[4];
#pragma unroll
  for (int ni = 0; ni < 4; ++ni) {
    int d = wid * 64 + ni * 16 + l15;
    vchunk[ni] = ((d >> 1) * 8 + ((((d & 1) << 2) | l4) ^ ((d >> 1) & 7))) * 8;
  }

  bf16x4_t pld;

  auto stage_load = [&](int ks) {
    pld = *(const bf16x4_t*)(purow + ks * 32 + sc4 * 4);
  };
  auto stage_finish = [&](int ks, int buf) {
    float4 w;
    w.x = (float)pld[0] * rr; w.y = (float)pld[1] * rr;
    w.z = (float)pld[2] * rr; w.w = (float)pld[3] * rr;
    *(float4*)(prow + (size_t)srow * NK + ks * 32 + sc4 * 4) = w;  // normalized W
    int sr = srow >> 1;
    int slot = (((srow & 1) << 2) | (sc4 >> 1)) ^ (sr & 7);
    union { bf16_t h[4]; uint2 u; } pk;
    pk.h[0] = (bf16_t)w.x; pk.h[1] = (bf16_t)w.y;
    pk.h[2] = (bf16_t)w.z; pk.h[3] = (bf16_t)w.w;
    *(uint2*)(&Ps[buf][((size_t)sr * 8 + slot) * 8 + (sc4 & 1) * 4]) = pk.u;
  };
  auto compute = [&](int ks, int cur) {
    const bf16_t* vsrc = vtb + (size_t)ks * (512 * 32);
    bf16x8 bv[4];
#pragma unroll
    for (int ni = 0; ni < 4; ++ni)  // direct global reads (L2-resident VT)
      bv[ni] = *(const bf16x8*)(vsrc + vchunk[ni]);
    bf16x8 af[4];
#pragma unroll
    for (int mi = 0; mi < 4; ++mi) {
      int row = mi * 16 + l15;
      af[mi] = *(const bf16x8*)(&Ps[cur][((row >> 1) * 8 + ((((row & 1) << 2) | l4) ^ ((row >> 1) & 7))) * 8]);
    }
#pragma unroll
    for (int mi = 0; mi < 4; ++mi)
#pragma unroll
      for (int ni = 0; ni < 4; ++ni)
        acc[mi][ni] = mfma16(af[mi], bv[ni], acc[mi][ni]);
  };

  stage_load(0);
  stage_finish(0, 0);
  __syncthreads();
#pragma unroll 1
  for (int ks = 0; ks < nsteps; ++ks) {
    int cur = ks & 1;
    if (ks + 1 < nsteps) stage_load(ks + 1);  // issue Pu read early
    compute(ks, cur);
    if (ks + 1 < nsteps) stage_finish(ks + 1, cur ^ 1);
    __syncthreads();
  }

  // zero-fill masked W tail (own rows only; own Pu reads already consumed)
  {
    float4 z = make_float4(0.f, 0.f, 0.f, 0.f);
    for (int c = nsteps * 32 + sc4 * 4; c < NK; c += 32)
      *(float4*)(prow + (size_t)srow * NK + c) = z;
  }

  float* crow = ctx + ((size_t)b * NQ + q0) * ND + wid * 64;
#pragma unroll
  for (int mi = 0; mi < 4; ++mi)
#pragma unroll
    for (int ni = 0; ni < 4; ++ni)
#pragma unroll
      for (int r = 0; r < 4; ++r)
        crow[(size_t)(mi * 16 + l4 * 4 + r) * ND + ni * 16 + l15] = acc[mi][ni][r];
}

// ---------------------------------------------------------------------------
extern "C" void kernel_launch(void* const* d_in, const int* in_sizes, int n_in,
                              void* d_out, int out_size, void* d_ws, size_t ws_size,
                              hipStream_t stream) {
  const float* Q = (const float*)d_in[0];
  const float* K = (const float*)d_in[1];
  const float* V = (const float*)d_in[2];
  const int* lens = (const int*)d_in[3];

  float* ctx = (float*)d_out;             // [B,Q,D]
  float* P = ctx + (size_t)NB * NQ * ND;  // [B,Q,K] weights region

  // ws layout: psum [B][16][NQ] f32 (2 MB) | Qb 32 MB | Kb 32 MB | VT 32 MB
  float* psum = (float*)d_ws;
  char* base = (char*)d_ws + (size_t)NB * 16 * NQ * sizeof(float);
  bf16_t* Qb = (bf16_t*)base;
  bf16_t* Kb = (bf16_t*)(base + (size_t)NB * NQ * ND * 2);
  bf16_t* VT = (bf16_t*)(base + (size_t)2 * NB * NQ * ND * 2);

  prep_kernel<<<dim3(256, 16, 3), 256, 0, stream>>>(Q, K, V, Qb, Kb, VT, lens);
  qk_kernel<<<dim3(4096), 256, 0, stream>>>(Qb, Kb, P, psum, lens);
  pv_kernel<<<dim3(512), 512, 0, stream>>>(P, VT, ctx, psum, lens);
}